// Round 4
// baseline (324.404 us; speedup 1.0000x reference)
//
#include <hip/hip_runtime.h>

// RhoLoss: total = sum over pairs (l1<=l2) of w * sum_s d1[s]^T O[s] d2[s]
// S=8, I=32, N=8, K_l = I*(2l+1)*N = {256, 768, 1280, 1792}
// O traffic = 356.5 MB streamed once (irreducible; every element used once).
//
// History: R2 static byte-balanced contiguous + nt = 65.4us. R3 single-atomic
// stealing = 355us (same-line atomic throughput 21.7ns/op serialized grid).
// R4 static hit/miss interleave = 68.3us (null + unit-split overhead).
// R5 = R2 + d2-hoist + unroll2 = 63.5us, but OccupancyPercent fell to 31%:
// most waves retire early, a minority runs 2-3x longer -> tail persists.
//
// R6: sharded work-stealing. 8 counters (one per blockIdx&7 ~ XCD), each in
// its own 128B line -> hand-out throughput 8x R3 (need only 17M/s/line,
// cap ~46M/s). Units strided across shards (u%8==shard) so each shard
// samples all pairs/regions -> no cross-shard imbalance. NV=12288 units
// (~29KB), statics cover 8192, ~0.5 steals/wave. Steal issued BEFORE
// processing current unit (latency hidden under ~29KB of loads).
// Inner loop = R5 verbatim.

#define NUM_S 8

typedef float vfloat4 __attribute__((ext_vector_type(4)));

// d layout in g_d: l0 @0 (2048), l1 @2048 (6144), l2 @8192 (10240), l3 @18432 (14336)
__device__ float g_d[32768];
__device__ __attribute__((aligned(128))) unsigned g_ctrs[8][32];  // [shard][pad]

#define NV_PER_SHARD 1536u   // 12288 units / 8 shards
#define Q_PER_SHARD  1024u   // static waves per shard (256 blocks * 4 waves)

__global__ __launch_bounds__(256) void compute_d_kernel(
    const float* __restrict__ ci0, const float* __restrict__ ct0,
    const float* __restrict__ ci1, const float* __restrict__ ct1,
    const float* __restrict__ ci2, const float* __restrict__ ct2,
    const float* __restrict__ ci3, const float* __restrict__ ct3,
    float* __restrict__ out) {
    const int t = blockIdx.x * 256 + threadIdx.x;  // 0..32767
    if (t == 0) *out = 0.0f;                       // d_out poisoned each call
    if (t < 8) g_ctrs[t][0] = Q_PER_SHARD;         // steal cursors
    float v;
    if (t < 2048)       v = ci0[t]         - ct0[t];
    else if (t < 8192)  v = ci1[t - 2048]  - ct1[t - 2048];
    else if (t < 18432) v = ci2[t - 8192]  - ct2[t - 8192];
    else                v = ci3[t - 18432] - ct3[t - 18432];
    g_d[t] = v;
}

// One unit: contiguous row range [lw*NROWS/NWP, (lw+1)*NROWS/NWP).
// K1,K2,NWP compile-time -> all div/mod become magic multiplies.
template <int K1, int K2, int W, int NWP>
__device__ __forceinline__ float pair_rows(const float* __restrict__ O,
                                           const float* __restrict__ d1,
                                           const float* __restrict__ d2,
                                           int lw, int lane) {
    constexpr int C2q    = K2 / 4;     // float4s per row
    constexpr int ROUNDS = C2q / 64;   // wave-wide float4 loads per row (1,3,5,7)
    constexpr int NROWS  = NUM_S * K1;

    const int r_beg = (int)(((long long)lw * NROWS) / NWP);
    const int r_end = (int)(((long long)(lw + 1) * NROWS) / NWP);

    const vfloat4* __restrict__ O4 = (const vfloat4*)O;

    float ax = 0.f, ay = 0.f, az = 0.f, aw = 0.f;

    int t = r_beg;
    while (t < r_end) {
        const int s        = t / K1;                 // structure index
        const int seg_full = (s + 1) * K1;           // next s boundary
        const int seg_end  = seg_full < r_end ? seg_full : r_end;

        // d2 row for this structure: loaded ONCE per segment (L2-hot, tiny)
        const vfloat4* __restrict__ v = (const vfloat4*)(d2 + s * K2) + lane;
        vfloat4 vv[ROUNDS];
#pragma unroll
        for (int j = 0; j < ROUNDS; ++j) vv[j] = v[j * 64];

        // inner loop: pure nt O-stream + FMA; 2 rows in flight
#pragma unroll 2
        for (int u = t; u < seg_end; ++u) {
            const vfloat4* __restrict__ o = O4 + (size_t)u * C2q + lane;
            vfloat4 ov[ROUNDS];
#pragma unroll
            for (int j = 0; j < ROUNDS; ++j)
                ov[j] = __builtin_nontemporal_load(o + j * 64);  // nt: no-allocate

            const float dd = d1[u];  // wave-uniform -> s_load

            float dx = 0.f, dy = 0.f, dz = 0.f, dw = 0.f;
#pragma unroll
            for (int j = 0; j < ROUNDS; ++j) {
                dx = fmaf(ov[j].x, vv[j].x, dx);
                dy = fmaf(ov[j].y, vv[j].y, dy);
                dz = fmaf(ov[j].z, vv[j].z, dz);
                dw = fmaf(ov[j].w, vv[j].w, dw);
            }
            ax = fmaf(dd, dx, ax);
            ay = fmaf(dd, dy, ay);
            az = fmaf(dd, dz, az);
            aw = fmaf(dd, dw, aw);
        }
        t = seg_end;
    }
    return (float)W * ((ax + ay) + (az + aw));
}

// 12288 units, byte-proportional (~29KB each). Cumulative bounds:
// p00 [0,72) p01 [72,289) p02 [289,650) p03 [650,1156) p11 [1156,1806)
// p12 [1806,2890) p13 [2890,4408) p22 [4408,6215) p23 [6215,8745)
// p33 [8745,12288)
__device__ __forceinline__ float do_unit(
    unsigned v, int lane,
    const float* __restrict__ O00, const float* __restrict__ O01,
    const float* __restrict__ O02, const float* __restrict__ O03,
    const float* __restrict__ O11, const float* __restrict__ O12,
    const float* __restrict__ O13, const float* __restrict__ O22,
    const float* __restrict__ O23, const float* __restrict__ O33) {
    const float* D0 = g_d;
    const float* D1 = g_d + 2048;
    const float* D2 = g_d + 8192;
    const float* D3 = g_d + 18432;

    if      (v <    72u) return pair_rows< 256,  256, 1,   72>(O00, D0, D0, (int)v,           lane);
    else if (v <   289u) return pair_rows< 256,  768, 2,  217>(O01, D0, D1, (int)(v -   72), lane);
    else if (v <   650u) return pair_rows< 256, 1280, 2,  361>(O02, D0, D2, (int)(v -  289), lane);
    else if (v <  1156u) return pair_rows< 256, 1792, 2,  506>(O03, D0, D3, (int)(v -  650), lane);
    else if (v <  1806u) return pair_rows< 768,  768, 1,  650>(O11, D1, D1, (int)(v - 1156), lane);
    else if (v <  2890u) return pair_rows< 768, 1280, 2, 1084>(O12, D1, D2, (int)(v - 1806), lane);
    else if (v <  4408u) return pair_rows< 768, 1792, 2, 1518>(O13, D1, D3, (int)(v - 2890), lane);
    else if (v <  6215u) return pair_rows<1280, 1280, 1, 1807>(O22, D2, D2, (int)(v - 4408), lane);
    else if (v <  8745u) return pair_rows<1280, 1792, 2, 2530>(O23, D2, D3, (int)(v - 6215), lane);
    else                 return pair_rows<1792, 1792, 1, 3543>(O33, D3, D3, (int)(v - 8745), lane);
}

__global__ __launch_bounds__(256) void rho_loss_kernel(
    const float* __restrict__ O00, const float* __restrict__ O01,
    const float* __restrict__ O02, const float* __restrict__ O03,
    const float* __restrict__ O11, const float* __restrict__ O12,
    const float* __restrict__ O13, const float* __restrict__ O22,
    const float* __restrict__ O23, const float* __restrict__ O33,
    float* __restrict__ out) {
    const int lane  = threadIdx.x & 63;
    const int lwid  = threadIdx.x >> 6;               // 0..3
    const unsigned shard = blockIdx.x & 7u;           // = XCD under round-robin
    const unsigned q     = (blockIdx.x >> 3) * 4u + (unsigned)lwid;  // 0..1023

    float acc = 0.f;
    unsigned u = 8u * q + shard;                      // static first unit
    for (;;) {
        // issue steal EARLY; latency hides under the ~29KB of loads below
        unsigned k = 0xffffffffu;
        if (lane == 0) k = atomicAdd(&g_ctrs[shard][0], 1u);

        acc += do_unit(u, lane, O00, O01, O02, O03, O11, O12, O13,
                       O22, O23, O33);

        k = (unsigned)__shfl((int)k, 0, 64);          // broadcast stolen idx
        if (k >= NV_PER_SHARD) break;
        u = 8u * k + shard;
    }

    // wave (64-lane) shuffle reduction
    for (int off = 32; off > 0; off >>= 1)
        acc += __shfl_down(acc, off, 64);

    __shared__ float wsum[4];
    if (lane == 0) wsum[lwid] = acc;
    __syncthreads();
    if (threadIdx.x == 0) {
        float s = wsum[0] + wsum[1] + wsum[2] + wsum[3];
        atomicAdd(out, s);
    }
}

extern "C" void kernel_launch(void* const* d_in, const int* in_sizes, int n_in,
                              void* d_out, int out_size, void* d_ws, size_t ws_size,
                              hipStream_t stream) {
    (void)in_sizes; (void)n_in; (void)d_ws; (void)ws_size; (void)out_size;

    const float* ci0 = (const float*)d_in[0];
    const float* ct0 = (const float*)d_in[1];
    const float* ci1 = (const float*)d_in[2];
    const float* ct1 = (const float*)d_in[3];
    const float* ci2 = (const float*)d_in[4];
    const float* ct2 = (const float*)d_in[5];
    const float* ci3 = (const float*)d_in[6];
    const float* ct3 = (const float*)d_in[7];
    const float* O00 = (const float*)d_in[8];
    const float* O01 = (const float*)d_in[9];
    const float* O02 = (const float*)d_in[10];
    const float* O03 = (const float*)d_in[11];
    const float* O11 = (const float*)d_in[12];
    const float* O12 = (const float*)d_in[13];
    const float* O13 = (const float*)d_in[14];
    const float* O22 = (const float*)d_in[15];
    const float* O23 = (const float*)d_in[16];
    const float* O33 = (const float*)d_in[17];

    // Stage deltas + zero d_out + init steal cursors (one dispatch).
    compute_d_kernel<<<128, 256, 0, stream>>>(ci0, ct0, ci1, ct1,
                                              ci2, ct2, ci3, ct3,
                                              (float*)d_out);

    // 2048 blocks * 4 waves = 8192 waves; 8 blocks/CU resident.
    rho_loss_kernel<<<2048, 256, 0, stream>>>(
        O00, O01, O02, O03, O11, O12, O13, O22, O23, O33, (float*)d_out);
}

// Round 5
// 318.524 us; speedup vs baseline: 1.0185x; 1.0185x over previous
//
#include <hip/hip_runtime.h>

// RhoLoss: total = sum over pairs (l1<=l2) of w * sum_s d1[s]^T O[s] d2[s]
// S=8, I=32, N=8, K_l = I*(2l+1)*N = {256, 768, 1280, 1792}
// O traffic = 356.5 MB streamed once (irreducible; every element used once).
//
// History: R2 static contiguous + nt = 65.4us. R3 single-atomic stealing =
// 355us (same-line atomic tput serialized grid). R4 static interleave =
// 68.3us (null). R5 = R2 + d2-hoist + unroll2 = 63.5us = 5.61 TB/s (89% of
// copy ceiling). R6 sharded stealing = 69.4us (VGPR 76 cut occupancy, strided
// units broke contiguity). Conclusion: no harvestable load imbalance exists.
//
// R7: granularity UP. 4096 waves x ~87 KB contiguous (was 8192 x 43.5 KB):
// halves the concurrent-stream count per HBM channel (DRAM page locality),
// keeps 16 waves/CU x 14 outstanding 1KB loads = plenty of MLP.
// Inner loop = R5 verbatim (d2 hoisted per s-segment, 2 rows in flight, nt).

#define NUM_S 8

typedef float vfloat4 __attribute__((ext_vector_type(4)));

// d layout in g_d: l0 @0 (2048), l1 @2048 (6144), l2 @8192 (10240), l3 @18432 (14336)
__device__ float g_d[32768];

__global__ __launch_bounds__(256) void compute_d_kernel(
    const float* __restrict__ ci0, const float* __restrict__ ct0,
    const float* __restrict__ ci1, const float* __restrict__ ct1,
    const float* __restrict__ ci2, const float* __restrict__ ct2,
    const float* __restrict__ ci3, const float* __restrict__ ct3,
    float* __restrict__ out) {
    const int t = blockIdx.x * 256 + threadIdx.x;  // 0..32767
    if (t == 0) *out = 0.0f;                       // d_out poisoned each call
    float v;
    if (t < 2048)       v = ci0[t]         - ct0[t];
    else if (t < 8192)  v = ci1[t - 2048]  - ct1[t - 2048];
    else if (t < 18432) v = ci2[t - 8192]  - ct2[t - 8192];
    else                v = ci3[t - 18432] - ct3[t - 18432];
    g_d[t] = v;
}

// One pair, one wave: contiguous row range [lw*NROWS/NWP, (lw+1)*NROWS/NWP).
// K1,K2,NWP compile-time -> all div/mod become magic multiplies.
template <int K1, int K2, int W, int NWP>
__device__ __forceinline__ float pair_rows(const float* __restrict__ O,
                                           const float* __restrict__ d1,
                                           const float* __restrict__ d2,
                                           int lw, int lane) {
    constexpr int C2q    = K2 / 4;     // float4s per row
    constexpr int ROUNDS = C2q / 64;   // wave-wide float4 loads per row (1,3,5,7)
    constexpr int NROWS  = NUM_S * K1;

    const int r_beg = (int)(((long long)lw * NROWS) / NWP);
    const int r_end = (int)(((long long)(lw + 1) * NROWS) / NWP);

    const vfloat4* __restrict__ O4 = (const vfloat4*)O;

    float ax = 0.f, ay = 0.f, az = 0.f, aw = 0.f;

    int t = r_beg;
    while (t < r_end) {
        const int s        = t / K1;                 // structure index
        const int seg_full = (s + 1) * K1;           // next s boundary
        const int seg_end  = seg_full < r_end ? seg_full : r_end;

        // d2 row for this structure: loaded ONCE per segment (L2-hot, tiny)
        const vfloat4* __restrict__ v = (const vfloat4*)(d2 + s * K2) + lane;
        vfloat4 vv[ROUNDS];
#pragma unroll
        for (int j = 0; j < ROUNDS; ++j) vv[j] = v[j * 64];

        // inner loop: pure nt O-stream + FMA; 2 rows in flight
#pragma unroll 2
        for (int u = t; u < seg_end; ++u) {
            const vfloat4* __restrict__ o = O4 + (size_t)u * C2q + lane;
            vfloat4 ov[ROUNDS];
#pragma unroll
            for (int j = 0; j < ROUNDS; ++j)
                ov[j] = __builtin_nontemporal_load(o + j * 64);  // nt: no-allocate

            const float dd = d1[u];  // wave-uniform

            float dx = 0.f, dy = 0.f, dz = 0.f, dw = 0.f;
#pragma unroll
            for (int j = 0; j < ROUNDS; ++j) {
                dx = fmaf(ov[j].x, vv[j].x, dx);
                dy = fmaf(ov[j].y, vv[j].y, dy);
                dz = fmaf(ov[j].z, vv[j].z, dz);
                dw = fmaf(ov[j].w, vv[j].w, dw);
            }
            ax = fmaf(dd, dx, ax);
            ay = fmaf(dd, dy, ay);
            az = fmaf(dd, dz, az);
            aw = fmaf(dd, dw, aw);
        }
        t = seg_end;
    }
    return (float)W * ((ax + ay) + (az + aw));
}

// Wave-range partition over 4096 waves, byte-proportional (~87 KB each):
// p00 [0,24) p01 [24,96) p02 [96,216) p03 [216,385) p11 [385,602)
// p12 [602,963) p13 [963,1469) p22 [1469,2071) p23 [2071,2914) p33 [2914,4096)
__global__ __launch_bounds__(256) void rho_loss_kernel(
    const float* __restrict__ O00, const float* __restrict__ O01,
    const float* __restrict__ O02, const float* __restrict__ O03,
    const float* __restrict__ O11, const float* __restrict__ O12,
    const float* __restrict__ O13, const float* __restrict__ O22,
    const float* __restrict__ O23, const float* __restrict__ O33,
    float* __restrict__ out) {
    const int lane = threadIdx.x & 63;
    const int wid  = blockIdx.x * 4 + (threadIdx.x >> 6);  // 0..4095

    const float* D0 = g_d;
    const float* D1 = g_d + 2048;
    const float* D2 = g_d + 8192;
    const float* D3 = g_d + 18432;

    float acc;
    if      (wid <   24) acc = pair_rows< 256,  256, 1,   24>(O00, D0, D0, wid,        lane);
    else if (wid <   96) acc = pair_rows< 256,  768, 2,   72>(O01, D0, D1, wid -   24, lane);
    else if (wid <  216) acc = pair_rows< 256, 1280, 2,  120>(O02, D0, D2, wid -   96, lane);
    else if (wid <  385) acc = pair_rows< 256, 1792, 2,  169>(O03, D0, D3, wid -  216, lane);
    else if (wid <  602) acc = pair_rows< 768,  768, 1,  217>(O11, D1, D1, wid -  385, lane);
    else if (wid <  963) acc = pair_rows< 768, 1280, 2,  361>(O12, D1, D2, wid -  602, lane);
    else if (wid < 1469) acc = pair_rows< 768, 1792, 2,  506>(O13, D1, D3, wid -  963, lane);
    else if (wid < 2071) acc = pair_rows<1280, 1280, 1,  602>(O22, D2, D2, wid - 1469, lane);
    else if (wid < 2914) acc = pair_rows<1280, 1792, 2,  843>(O23, D2, D3, wid - 2071, lane);
    else                 acc = pair_rows<1792, 1792, 1, 1182>(O33, D3, D3, wid - 2914, lane);

    // wave (64-lane) shuffle reduction
    for (int off = 32; off > 0; off >>= 1)
        acc += __shfl_down(acc, off, 64);

    __shared__ float wsum[4];
    const int lwid = threadIdx.x >> 6;
    if (lane == 0) wsum[lwid] = acc;
    __syncthreads();
    if (threadIdx.x == 0) {
        float s = wsum[0] + wsum[1] + wsum[2] + wsum[3];
        atomicAdd(out, s);
    }
}

extern "C" void kernel_launch(void* const* d_in, const int* in_sizes, int n_in,
                              void* d_out, int out_size, void* d_ws, size_t ws_size,
                              hipStream_t stream) {
    (void)in_sizes; (void)n_in; (void)d_ws; (void)ws_size; (void)out_size;

    const float* ci0 = (const float*)d_in[0];
    const float* ct0 = (const float*)d_in[1];
    const float* ci1 = (const float*)d_in[2];
    const float* ct1 = (const float*)d_in[3];
    const float* ci2 = (const float*)d_in[4];
    const float* ct2 = (const float*)d_in[5];
    const float* ci3 = (const float*)d_in[6];
    const float* ct3 = (const float*)d_in[7];
    const float* O00 = (const float*)d_in[8];
    const float* O01 = (const float*)d_in[9];
    const float* O02 = (const float*)d_in[10];
    const float* O03 = (const float*)d_in[11];
    const float* O11 = (const float*)d_in[12];
    const float* O12 = (const float*)d_in[13];
    const float* O13 = (const float*)d_in[14];
    const float* O22 = (const float*)d_in[15];
    const float* O23 = (const float*)d_in[16];
    const float* O33 = (const float*)d_in[17];

    // Stage deltas + zero d_out (one dispatch, no separate memset).
    compute_d_kernel<<<128, 256, 0, stream>>>(ci0, ct0, ci1, ct1,
                                              ci2, ct2, ci3, ct3,
                                              (float*)d_out);

    // 1024 blocks * 4 waves = 4096 waves; 4 blocks/CU, 16 waves/CU.
    rho_loss_kernel<<<1024, 256, 0, stream>>>(
        O00, O01, O02, O03, O11, O12, O13, O22, O23, O33, (float*)d_out);
}

// Round 6
// 317.972 us; speedup vs baseline: 1.0202x; 1.0017x over previous
//
#include <hip/hip_runtime.h>

// RhoLoss: total = sum over pairs (l1<=l2) of w * sum_s d1[s]^T O[s] d2[s]
// S=8, I=32, N=8, K_l = I*(2l+1)*N = {256, 768, 1280, 1792}
// O traffic = 356.5 MB streamed once (irreducible; every element used once,
// fp32 required, inputs asymmetric -> no symmetry savings).
//
// FINAL (= R5, best measured 63.5us rho / 318.6us bench = 5.61 TB/s
// effective, 89% of the 6.29 TB/s copy-achievable fabric ceiling).
//
// Ledger of probed levers:
//  R2  nt (no-allocate) loads on O: 2.9 -> 5.45 TB/s. The decisive lever:
//      streaming misses must not evict the harness-restored dirty LLC lines.
//  R5  d2-row hoisted per s-segment (was re-loaded every row) + unroll 2:
//      5.45 -> 5.61 TB/s.
//  R3  single-atomic work stealing: 5.5x WORSE (same-line atomic throughput
//      21.7ns/op serialized the grid).
//  R4  static hit/miss interleave (32768 units): null -> no positional
//      LLC/HBM speed split exists.
//  R6  sharded (per-XCD) stealing: worse (VGPR 76 cut occupancy; strided
//      units broke stream contiguity).
//  R7  87KB/wave granularity (4096 waves): worse. 43.5KB contiguous/wave
//      at full 32-wave/CU residency is the optimum.
// Conclusion: supply-limited at ~89% of fabric ceiling; no harvestable
// imbalance; traffic irreducible. Structural roofline.

#define NUM_S 8

typedef float vfloat4 __attribute__((ext_vector_type(4)));

// d layout in g_d: l0 @0 (2048), l1 @2048 (6144), l2 @8192 (10240), l3 @18432 (14336)
__device__ float g_d[32768];

__global__ __launch_bounds__(256) void compute_d_kernel(
    const float* __restrict__ ci0, const float* __restrict__ ct0,
    const float* __restrict__ ci1, const float* __restrict__ ct1,
    const float* __restrict__ ci2, const float* __restrict__ ct2,
    const float* __restrict__ ci3, const float* __restrict__ ct3,
    float* __restrict__ out) {
    const int t = blockIdx.x * 256 + threadIdx.x;  // 0..32767
    if (t == 0) *out = 0.0f;                       // d_out poisoned each call
    float v;
    if (t < 2048)       v = ci0[t]         - ct0[t];
    else if (t < 8192)  v = ci1[t - 2048]  - ct1[t - 2048];
    else if (t < 18432) v = ci2[t - 8192]  - ct2[t - 8192];
    else                v = ci3[t - 18432] - ct3[t - 18432];
    g_d[t] = v;
}

// One pair, one wave: contiguous row range [lw*NROWS/NWP, (lw+1)*NROWS/NWP).
// K1,K2,NWP compile-time -> all div/mod become magic multiplies.
template <int K1, int K2, int W, int NWP>
__device__ __forceinline__ float pair_rows(const float* __restrict__ O,
                                           const float* __restrict__ d1,
                                           const float* __restrict__ d2,
                                           int lw, int lane) {
    constexpr int C2q    = K2 / 4;     // float4s per row
    constexpr int ROUNDS = C2q / 64;   // wave-wide float4 loads per row (1,3,5,7)
    constexpr int NROWS  = NUM_S * K1;

    const int r_beg = (int)(((long long)lw * NROWS) / NWP);
    const int r_end = (int)(((long long)(lw + 1) * NROWS) / NWP);

    const vfloat4* __restrict__ O4 = (const vfloat4*)O;

    float ax = 0.f, ay = 0.f, az = 0.f, aw = 0.f;

    int t = r_beg;
    while (t < r_end) {
        const int s        = t / K1;                 // structure index
        const int seg_full = (s + 1) * K1;           // next s boundary
        const int seg_end  = seg_full < r_end ? seg_full : r_end;

        // d2 row for this structure: loaded ONCE per segment (L2-hot, tiny)
        const vfloat4* __restrict__ v = (const vfloat4*)(d2 + s * K2) + lane;
        vfloat4 vv[ROUNDS];
#pragma unroll
        for (int j = 0; j < ROUNDS; ++j) vv[j] = v[j * 64];

        // inner loop: pure nt O-stream + FMA; 2 rows in flight
#pragma unroll 2
        for (int u = t; u < seg_end; ++u) {
            const vfloat4* __restrict__ o = O4 + (size_t)u * C2q + lane;
            vfloat4 ov[ROUNDS];
#pragma unroll
            for (int j = 0; j < ROUNDS; ++j)
                ov[j] = __builtin_nontemporal_load(o + j * 64);  // nt: no-allocate

            const float dd = d1[u];  // wave-uniform

            float dx = 0.f, dy = 0.f, dz = 0.f, dw = 0.f;
#pragma unroll
            for (int j = 0; j < ROUNDS; ++j) {
                dx = fmaf(ov[j].x, vv[j].x, dx);
                dy = fmaf(ov[j].y, vv[j].y, dy);
                dz = fmaf(ov[j].z, vv[j].z, dz);
                dw = fmaf(ov[j].w, vv[j].w, dw);
            }
            ax = fmaf(dd, dx, ax);
            ay = fmaf(dd, dy, ay);
            az = fmaf(dd, dz, az);
            aw = fmaf(dd, dw, aw);
        }
        t = seg_end;
    }
    return (float)W * ((ax + ay) + (az + aw));
}

// Wave-range partition over 8192 waves, proportional to per-pair bytes
// (each wave ~43.5 KB contiguous).
__global__ __launch_bounds__(256) void rho_loss_kernel(
    const float* __restrict__ O00, const float* __restrict__ O01,
    const float* __restrict__ O02, const float* __restrict__ O03,
    const float* __restrict__ O11, const float* __restrict__ O12,
    const float* __restrict__ O13, const float* __restrict__ O22,
    const float* __restrict__ O23, const float* __restrict__ O33,
    float* __restrict__ out) {
    const int lane = threadIdx.x & 63;
    const int wid  = blockIdx.x * 4 + (threadIdx.x >> 6);  // 0..8191

    const float* D0 = g_d;
    const float* D1 = g_d + 2048;
    const float* D2 = g_d + 8192;
    const float* D3 = g_d + 18432;

    float acc;
    // ranges: p00 [0,47) p01 [47,192) p02 [192,433) p03 [433,770)
    //         p11 [770,1204) p12 [1204,1927) p13 [1927,2939)
    //         p22 [2939,4144) p23 [4144,5831) p33 [5831,8192)
    if      (wid <   47) acc = pair_rows< 256,  256, 1,   47>(O00, D0, D0, wid,        lane);
    else if (wid <  192) acc = pair_rows< 256,  768, 2,  145>(O01, D0, D1, wid -   47, lane);
    else if (wid <  433) acc = pair_rows< 256, 1280, 2,  241>(O02, D0, D2, wid -  192, lane);
    else if (wid <  770) acc = pair_rows< 256, 1792, 2,  337>(O03, D0, D3, wid -  433, lane);
    else if (wid < 1204) acc = pair_rows< 768,  768, 1,  434>(O11, D1, D1, wid -  770, lane);
    else if (wid < 1927) acc = pair_rows< 768, 1280, 2,  723>(O12, D1, D2, wid - 1204, lane);
    else if (wid < 2939) acc = pair_rows< 768, 1792, 2, 1012>(O13, D1, D3, wid - 1927, lane);
    else if (wid < 4144) acc = pair_rows<1280, 1280, 1, 1205>(O22, D2, D2, wid - 2939, lane);
    else if (wid < 5831) acc = pair_rows<1280, 1792, 2, 1687>(O23, D2, D3, wid - 4144, lane);
    else                 acc = pair_rows<1792, 1792, 1, 2361>(O33, D3, D3, wid - 5831, lane);

    // wave (64-lane) shuffle reduction
    for (int off = 32; off > 0; off >>= 1)
        acc += __shfl_down(acc, off, 64);

    __shared__ float wsum[4];
    const int lwid = threadIdx.x >> 6;
    if (lane == 0) wsum[lwid] = acc;
    __syncthreads();
    if (threadIdx.x == 0) {
        float s = wsum[0] + wsum[1] + wsum[2] + wsum[3];
        atomicAdd(out, s);
    }
}

extern "C" void kernel_launch(void* const* d_in, const int* in_sizes, int n_in,
                              void* d_out, int out_size, void* d_ws, size_t ws_size,
                              hipStream_t stream) {
    (void)in_sizes; (void)n_in; (void)d_ws; (void)ws_size; (void)out_size;

    const float* ci0 = (const float*)d_in[0];
    const float* ct0 = (const float*)d_in[1];
    const float* ci1 = (const float*)d_in[2];
    const float* ct1 = (const float*)d_in[3];
    const float* ci2 = (const float*)d_in[4];
    const float* ct2 = (const float*)d_in[5];
    const float* ci3 = (const float*)d_in[6];
    const float* ct3 = (const float*)d_in[7];
    const float* O00 = (const float*)d_in[8];
    const float* O01 = (const float*)d_in[9];
    const float* O02 = (const float*)d_in[10];
    const float* O03 = (const float*)d_in[11];
    const float* O11 = (const float*)d_in[12];
    const float* O12 = (const float*)d_in[13];
    const float* O13 = (const float*)d_in[14];
    const float* O22 = (const float*)d_in[15];
    const float* O23 = (const float*)d_in[16];
    const float* O33 = (const float*)d_in[17];

    // Stage deltas + zero d_out (one dispatch, no separate memset).
    compute_d_kernel<<<128, 256, 0, stream>>>(ci0, ct0, ci1, ct1,
                                              ci2, ct2, ci3, ct3,
                                              (float*)d_out);

    // 2048 blocks * 4 waves = 8192 waves; 8 blocks/CU, full 32-wave/CU residency.
    rho_loss_kernel<<<2048, 256, 0, stream>>>(
        O00, O01, O02, O03, O11, O12, O13, O22, O23, O33, (float*)d_out);
}